// Round 2
// baseline (498.473 us; speedup 1.0000x reference)
//
#include <hip/hip_runtime.h>

// LIF recurrence: X [B,T,N] f32 -> spikes [B,T,N] f32. B=32, T=64, N=32768.
// Independent per (b,n); sequential over t. Stream-bound: 537 MB min traffic.
//
// R3 analysis: the five largest profiled dispatches are harness poison-fills
// (163 us each @ 6.6 TB/s, 1 GiB) -- the lif kernel itself is < 163 us, so
// the 441 us score carries ~326 us of fixed fill overhead. Kernel-side gap
// to the ~85 us stream floor attacked with:
//   - float4 (16 B/lane) loads+stores: half the vmem requests of float2
//   - depth-4 prefetch: 4 KB in flight/wave -> 64 KB/CU (Little's-law safe)
//   - nontemporal stores: spikes never re-read; keep writes out of L2/L3
// Occupancy drops 32 -> 16 waves/CU but in-flight bytes per CU double.
// Strict fp preserved (contract off, true /5.0f divide): absmax must stay 0.
// (R4 = identical resubmit of R3: round-1 failure was a container flake,
//  no kernel-side diagnostics; bounds re-verified, max index = B*T*N4 - 1.)

typedef float f32x4 __attribute__((ext_vector_type(4)));

constexpr int B = 32;
constexpr int T = 64;
constexpr int N = 32768;
constexpr int N4 = N / 4;            // 8192 float4 per (b,t) row
constexpr int NTHREADS = B * N4;     // 262144 threads = 4096 waves

__global__ __launch_bounds__(256) void lif_kernel(const f32x4* __restrict__ X,
                                                  f32x4* __restrict__ out) {
    // Match numpy's separately-rounded mul/add (no FMA contraction): fusing
    // changes rounding and can flip threshold decisions.
#pragma clang fp contract(off)
    const int i = blockIdx.x * blockDim.x + threadIdx.x;  // [0, B*N4)
    const int b = i >> 13;               // i / N4   (N4 = 8192)
    const int n4 = i & (N4 - 1);         // i % N4
    const int base = b * (T * N4) + n4;  // <= 16.7M float4 -> fits int

    const f32x4* __restrict__ Xp = X + base;
    f32x4* __restrict__ Op = out + base;

    // persistent per-neuron state, one per vector component
    float mx = 0.f, my = 0.f, mz = 0.f, mw = 0.f;
    float cx = 0.f, cy = 0.f, cz = 0.f, cw = 0.f;

    // depth-4 software pipeline in NAMED registers (runtime-indexed arrays
    // would spill to scratch -- rule #20). xa..xd hold x(t)..x(t+3).
    f32x4 xa = Xp[0 * N4];
    f32x4 xb = Xp[1 * N4];
    f32x4 xc = Xp[2 * N4];
    f32x4 xd = Xp[3 * N4];

#define LIF1(mem, ca, xin, sout)                              \
    {                                                         \
        float m_ = mem / 5.0f + (1.0f + 0.1f * ca) * (xin);   \
        float s_ = ((m_ - 0.5f) > 0.0f) ? 1.0f : 0.0f;        \
        mem = (1.0f - s_) * m_;                               \
        ca = 0.5f * ca + (1.0f - s_);                         \
        sout = s_;                                            \
    }

    // clamp keeps the prefetch unconditional (branchless, stays in flight);
    // tail substeps just re-read slice T-1 (L1/L2 hit, harmless).
#define SUBSTEP(xreg, j)                                      \
    {                                                         \
        const f32x4 xv_ = xreg;                               \
        int tp_ = t + 4 + (j);                                \
        tp_ = (tp_ < T) ? tp_ : (T - 1);                      \
        xreg = Xp[tp_ * N4];                                  \
        f32x4 sv_;                                            \
        LIF1(mx, cx, xv_.x, sv_.x);                           \
        LIF1(my, cy, xv_.y, sv_.y);                           \
        LIF1(mz, cz, xv_.z, sv_.z);                           \
        LIF1(mw, cw, xv_.w, sv_.w);                           \
        __builtin_nontemporal_store(sv_, Op + (t + (j)) * N4);\
    }

    for (int t = 0; t < T; t += 4) {
        SUBSTEP(xa, 0)
        SUBSTEP(xb, 1)
        SUBSTEP(xc, 2)
        SUBSTEP(xd, 3)
    }
#undef SUBSTEP
#undef LIF1
}

extern "C" void kernel_launch(void* const* d_in, const int* in_sizes, int n_in,
                              void* d_out, int out_size, void* d_ws, size_t ws_size,
                              hipStream_t stream) {
    const f32x4* X = (const f32x4*)d_in[0];
    f32x4* out = (f32x4*)d_out;
    const int block = 256;
    const int grid = NTHREADS / block;  // 1024 blocks
    lif_kernel<<<grid, block, 0, stream>>>(X, out);
}

// Round 3
// 466.813 us; speedup vs baseline: 1.0678x; 1.0678x over previous
//
#include <hip/hip_runtime.h>

// LIF recurrence: X [B,T,N] f32 -> spikes [B,T,N] f32. B=32, T=64, N=32768.
// Independent per (b,n); sequential over t. Stream-bound: 537 MB min traffic.
//
// R5: R4's nontemporal stores were the regression (210 us @ 1.9 TB/s,
// VALUBusy 15.8%). vmcnt drains IN ISSUE ORDER and is shared by loads and
// stores: waiting for a prefetched load implicitly waits for every older
// store. nt stores bypass L2 and retire at HBM latency (~900 cy) instead of
// L2-ack latency, so each step serialized on store retirement. Fix: regular
// stores (L2-absorbed, fast retire). Keep float4 16 B/lane + depth-4
// prefetch (64 KB/CU of loads in flight, Little's-law safe at 16 waves/CU).
// Strict fp preserved (contract off, true /5.0f divide): absmax must stay 0.

typedef float f32x4 __attribute__((ext_vector_type(4)));

constexpr int B = 32;
constexpr int T = 64;
constexpr int N = 32768;
constexpr int N4 = N / 4;            // 8192 float4 per (b,t) row
constexpr int NTHREADS = B * N4;     // 262144 threads = 4096 waves

__global__ __launch_bounds__(256) void lif_kernel(const f32x4* __restrict__ X,
                                                  f32x4* __restrict__ out) {
    // Match numpy's separately-rounded mul/add (no FMA contraction): fusing
    // changes rounding and can flip threshold decisions.
#pragma clang fp contract(off)
    const int i = blockIdx.x * blockDim.x + threadIdx.x;  // [0, B*N4)
    const int b = i >> 13;               // i / N4   (N4 = 8192)
    const int n4 = i & (N4 - 1);         // i % N4
    const int base = b * (T * N4) + n4;  // <= 16.7M float4 -> fits int

    const f32x4* __restrict__ Xp = X + base;
    f32x4* __restrict__ Op = out + base;

    // persistent per-neuron state, one per vector component
    float mx = 0.f, my = 0.f, mz = 0.f, mw = 0.f;
    float cx = 0.f, cy = 0.f, cz = 0.f, cw = 0.f;

    // depth-4 software pipeline in NAMED registers (runtime-indexed arrays
    // would spill to scratch -- rule #20). xa..xd hold x(t)..x(t+3).
    f32x4 xa = Xp[0 * N4];
    f32x4 xb = Xp[1 * N4];
    f32x4 xc = Xp[2 * N4];
    f32x4 xd = Xp[3 * N4];

#define LIF1(mem, ca, xin, sout)                              \
    {                                                         \
        float m_ = mem / 5.0f + (1.0f + 0.1f * ca) * (xin);   \
        float s_ = ((m_ - 0.5f) > 0.0f) ? 1.0f : 0.0f;        \
        mem = (1.0f - s_) * m_;                               \
        ca = 0.5f * ca + (1.0f - s_);                         \
        sout = s_;                                            \
    }

    // clamp keeps the prefetch unconditional (branchless, stays in flight);
    // tail substeps just re-read slice T-1 (L1/L2 hit, harmless).
#define SUBSTEP(xreg, j)                                      \
    {                                                         \
        const f32x4 xv_ = xreg;                               \
        int tp_ = t + 4 + (j);                                \
        tp_ = (tp_ < T) ? tp_ : (T - 1);                      \
        xreg = Xp[tp_ * N4];                                  \
        f32x4 sv_;                                            \
        LIF1(mx, cx, xv_.x, sv_.x);                           \
        LIF1(my, cy, xv_.y, sv_.y);                           \
        LIF1(mz, cz, xv_.z, sv_.z);                           \
        LIF1(mw, cw, xv_.w, sv_.w);                           \
        Op[(t + (j)) * N4] = sv_;                             \
    }

    for (int t = 0; t < T; t += 4) {
        SUBSTEP(xa, 0)
        SUBSTEP(xb, 1)
        SUBSTEP(xc, 2)
        SUBSTEP(xd, 3)
    }
#undef SUBSTEP
#undef LIF1
}

extern "C" void kernel_launch(void* const* d_in, const int* in_sizes, int n_in,
                              void* d_out, int out_size, void* d_ws, size_t ws_size,
                              hipStream_t stream) {
    const f32x4* X = (const f32x4*)d_in[0];
    f32x4* out = (f32x4*)d_out;
    const int block = 256;
    const int grid = NTHREADS / block;  // 1024 blocks
    lif_kernel<<<grid, block, 0, stream>>>(X, out);
}

// Round 4
// 436.960 us; speedup vs baseline: 1.1408x; 1.0683x over previous
//
#include <hip/hip_runtime.h>

// LIF recurrence: X [B,T,N] f32 -> spikes [B,T,N] f32. B=32, T=64, N=32768.
// Independent per (b,n); sequential over t. Stream-bound: 537 MB app traffic
// (HBM-side ~404 MB: L3 absorbs ~half the X reads, FETCH=132MB WRITE=262MB).
//
// R6: A/B across R0/R3 shows occupancy beats vector width for this
// latency-bound mixed read+write stream:
//   float2 @32 waves/CU depth-2  ~115 us   (R0)
//   float4 @16 waves/CU depth-4   178 us   (R3, regular stores)
//   float4 @16 waves/CU depth-4 + nt-store 210 us (R2: nt stores retire at
//     HBM latency and vmcnt drains in issue order -> serialized; reverted)
// More waves = more independent vmem queues + store issue slots. So: float2
// (8192 waves = 100% launch occupancy) and KEEP depth-4 prefetch: 2 KB/wave
// in flight -> 128 KB/CU, 2x R0. Regular stores (L2-absorbed fast retire).
// Strict fp preserved (contract off, true /5.0f divide): absmax must stay 0.

constexpr int B = 32;
constexpr int T = 64;
constexpr int N = 32768;
constexpr int N2 = N / 2;            // 16384 float2 per (b,t) row
constexpr int NTHREADS = B * N2;     // 524288 threads = 8192 waves

__global__ __launch_bounds__(256) void lif_kernel(const float2* __restrict__ X,
                                                  float2* __restrict__ out) {
    // Match numpy's separately-rounded mul/add (no FMA contraction): fusing
    // changes rounding and can flip threshold decisions.
#pragma clang fp contract(off)
    const int i = blockIdx.x * blockDim.x + threadIdx.x;  // [0, B*N2)
    const int b = i >> 14;               // i / N2   (N2 = 16384)
    const int n2 = i & (N2 - 1);         // i % N2
    const int base = b * (T * N2) + n2;  // <= 33.5M float2 -> fits int

    const float2* __restrict__ Xp = X + base;
    float2* __restrict__ Op = out + base;

    // persistent per-neuron state, one per vector component
    float mx = 0.f, my = 0.f;
    float cx = 0.f, cy = 0.f;

    // depth-4 software pipeline in NAMED registers (runtime-indexed arrays
    // would spill to scratch -- rule #20). xa..xd hold x(t)..x(t+3).
    float2 xa = Xp[0 * N2];
    float2 xb = Xp[1 * N2];
    float2 xc = Xp[2 * N2];
    float2 xd = Xp[3 * N2];

#define LIF1(mem, ca, xin, sout)                              \
    {                                                         \
        float m_ = mem / 5.0f + (1.0f + 0.1f * ca) * (xin);   \
        float s_ = ((m_ - 0.5f) > 0.0f) ? 1.0f : 0.0f;        \
        mem = (1.0f - s_) * m_;                               \
        ca = 0.5f * ca + (1.0f - s_);                         \
        sout = s_;                                            \
    }

    // clamp keeps the prefetch unconditional (branchless, stays in flight);
    // tail substeps just re-read slice T-1 (L1/L2 hit, harmless).
#define SUBSTEP(xreg, j)                                      \
    {                                                         \
        const float2 xv_ = xreg;                              \
        int tp_ = t + 4 + (j);                                \
        tp_ = (tp_ < T) ? tp_ : (T - 1);                      \
        xreg = Xp[tp_ * N2];                                  \
        float2 sv_;                                           \
        LIF1(mx, cx, xv_.x, sv_.x);                           \
        LIF1(my, cy, xv_.y, sv_.y);                           \
        Op[(t + (j)) * N2] = sv_;                             \
    }

    for (int t = 0; t < T; t += 4) {
        SUBSTEP(xa, 0)
        SUBSTEP(xb, 1)
        SUBSTEP(xc, 2)
        SUBSTEP(xd, 3)
    }
#undef SUBSTEP
#undef LIF1
}

extern "C" void kernel_launch(void* const* d_in, const int* in_sizes, int n_in,
                              void* d_out, int out_size, void* d_ws, size_t ws_size,
                              hipStream_t stream) {
    const float2* X = (const float2*)d_in[0];
    float2* out = (float2*)d_out;
    const int block = 256;
    const int grid = NTHREADS / block;  // 2048 blocks
    lif_kernel<<<grid, block, 0, stream>>>(X, out);
}

// Round 5
// 427.525 us; speedup vs baseline: 1.1659x; 1.0221x over previous
//
#include <hip/hip_runtime.h>

// LIF recurrence: X [B,T,N] f32 -> spikes [B,T,N] f32. B=32, T=64, N=32768.
// Independent per (b,n); sequential over t. Stream-bound: 537 MB app traffic
// (HBM-side ~394 MB: L3 absorbs ~half the X reads; FETCH=132MB WRITE=262MB).
//
// R7: rolling-pipeline post-mortem (R0 d2 ~153us == R4 d4 ~148us, both at
// only ~2.7 TB/s HBM): depth didn't matter because vmcnt is ONE in-order
// counter shared by loads and stores. In a rolling pipeline (load(t+4);
// compute; store(t)) the wait for x(t) sits behind 4 younger-issued stores,
// so every step's load-wait also waits for write-acks under a 1.8 TB/s
// write stream. Deeper prefetch just adds more stores to the chain.
//
// Fix: ISSUE ALL 64 LOADS BEFORE ANY STORE. One scalar float per thread
// (1M threads); the full time series = 64 VGPRs. Load burst, then a
// sched_barrier(0) fence so the compiler cannot sink loads into the compute
// loop, then fully-unrolled compute+store (constant indices -> registers,
// no scratch). With loads-before-stores, the in-order vmcnt retirement
// means waiting for x(t) NEVER waits on a store: oldest queue entries are
// always loads. Store backpressure can throttle store issue only, not the
// read pipeline. ~80 VGPR -> 6 waves/SIMD, ~16KB reads in flight per wave.
// Strict fp preserved (contract off, true /5.0f divide): absmax must stay 0.

constexpr int B = 32;
constexpr int T = 64;
constexpr int N = 32768;
constexpr int NTHREADS = B * N;      // 1,048,576 threads = 16384 waves

__global__ __launch_bounds__(256) void lif_kernel(const float* __restrict__ X,
                                                  float* __restrict__ out) {
    // Match numpy's separately-rounded mul/add (no FMA contraction): fusing
    // changes rounding and can flip threshold decisions.
#pragma clang fp contract(off)
    const int i = blockIdx.x * blockDim.x + threadIdx.x;  // [0, B*N)
    const int b = i >> 15;               // i / N   (N = 32768)
    const int n = i & (N - 1);           // i % N
    const int base = b * (T * N) + n;    // <= 67.1M floats -> fits int

    const float* __restrict__ Xp = X + base;
    float* __restrict__ Op = out + base;

    // Phase 1: issue the ENTIRE read burst. Fully unrolled, constant
    // indices -> xs[] promotes to 64 VGPRs (runtime indexing would spill).
    float xs[T];
#pragma unroll
    for (int t = 0; t < T; ++t) {
        xs[t] = Xp[t * N];
    }

    // Fence: nothing from below may be scheduled before this point, so no
    // store (or compute) can be interleaved ahead of any load issue.
    __builtin_amdgcn_sched_barrier(0);

    // Phase 2: sequential LIF over t, storing each spike as computed.
    // Waiting for xs[t] only requires the oldest (t+1) queue entries --
    // all loads -- to have retired; stores issued after never gate it.
    float mem = 0.f, ca = 0.f;
#pragma unroll
    for (int t = 0; t < T; ++t) {
        float m = mem / 5.0f + (1.0f + 0.1f * ca) * xs[t];
        float s = ((m - 0.5f) > 0.0f) ? 1.0f : 0.0f;
        mem = (1.0f - s) * m;
        ca = 0.5f * ca + (1.0f - s);
        Op[t * N] = s;
    }
}

extern "C" void kernel_launch(void* const* d_in, const int* in_sizes, int n_in,
                              void* d_out, int out_size, void* d_ws, size_t ws_size,
                              hipStream_t stream) {
    const float* X = (const float*)d_in[0];
    float* out = (float*)d_out;
    const int block = 256;
    const int grid = NTHREADS / block;  // 4096 blocks
    lif_kernel<<<grid, block, 0, stream>>>(X, out);
}